// Round 1
// baseline (280.057 us; speedup 1.0000x reference)
//
#include <hip/hip_runtime.h>

#define NTOK 98
#define NPAD 112
#define CDIM 128
#define SCALE 0.17677669529663687f

typedef short bf16x8 __attribute__((ext_vector_type(8)));
typedef float f32x4 __attribute__((ext_vector_type(4)));

__device__ __forceinline__ unsigned short f2bf(float f) {
  union { float f; unsigned u; } v; v.f = f;
  unsigned r = v.u + 0x7FFFu + ((v.u >> 16) & 1u);
  return (unsigned short)(r >> 16);
}

// XOR swizzle for [rows][128] bf16 LDS tiles: kills the 16-way bank conflict on
// stride-256B ds_read_b128 fragment reads (guide G4 / T2). Element-index form.
__device__ __forceinline__ int swz(int row, int col) {
  return row * 128 + (col ^ ((row & 7) << 3));
}

__global__ __launch_bounds__(512)
void win_attn_kernel(const float* __restrict__ x,
                     const float* __restrict__ mask,
                     const float* __restrict__ qkv_w,
                     const float* __restrict__ qkv_b,
                     const float* __restrict__ rpb,
                     const float* __restrict__ proj_w,
                     const float* __restrict__ proj_b,
                     float* __restrict__ out, int nW)
{
  __shared__ __align__(16) unsigned short xs_o[NPAD * 128];   // x, later attn-out o
  __shared__ __align__(16) unsigned short kb[NPAD * 128];     // k (all heads)
  __shared__ __align__(16) unsigned short vT[128 * 128];      // v transposed [chan][token]
  __shared__ __align__(16) unsigned short p2[2][NPAD * 128];  // P dbuf; p2[0] doubles as q transit
  __shared__ short mcode[NPAD];

  const int tid = threadIdx.x;
  const int lane = tid & 63;
  const int wv = tid >> 6;      // wave 0..7
  const int lm = lane & 15;
  const int lg = lane >> 4;
  const int blk = blockIdx.x;
  const float* xblk = x + (size_t)blk * (NTOK * CDIM);
  const float* maskw = mask + (size_t)(blk % nW) * (NTOK * NTOK);

  // ---- init: rel-pos code LUT (idx = mcode[m]-mcode[n]+253), stage x, zero pads ----
  if (tid < NPAD) {
    int t = tid < NTOK ? tid : NTOK - 1;
    int d = t / 49, rem = t % 49;
    mcode[tid] = (short)(d * 169 + (rem / 7) * 13 + (rem % 7));
  }
  for (int v = tid; v < NPAD * 32; v += 512) {
    int row = v >> 5, c4 = (v & 31) << 2;
    float4 f = make_float4(0.f, 0.f, 0.f, 0.f);
    if (row < NTOK) f = *(const float4*)(xblk + row * CDIM + c4);
    uint2 u;
    u.x = (unsigned)f2bf(f.x) | ((unsigned)f2bf(f.y) << 16);
    u.y = (unsigned)f2bf(f.z) | ((unsigned)f2bf(f.w) << 16);
    *(uint2*)&xs_o[swz(row, c4)] = u;
  }
  for (int v = tid; v < 128 * 16; v += 512)   // vT token-pad 112..127 = 0 (P there is 0; avoid NaN*0)
    vT[swz(v >> 4, 112 + (v & 15))] = 0;
  for (int v = tid; v < NPAD * 16; v += 512)  // p2[1] K-pad cols = 0
    p2[1][swz(v >> 4, 112 + (v & 15))] = 0;
  __syncthreads();

  // ---------------- GEMM1: qkv = x @ Wqkv^T + b ----------------
  {
    bf16x8 Bw[3][4];
    float bval[3];
#pragma unroll
    for (int jj = 0; jj < 3; ++jj) {
      int njg = jj * 8 + wv;                  // n-tile 0..23 (q:0-7, k:8-15, v:16-23)
      int row = njg * 16 + lm;
      bval[jj] = qkv_b[njg * 16 + lm];
#pragma unroll
      for (int kk = 0; kk < 4; ++kk) {
        const float* p = qkv_w + row * CDIM + kk * 32 + lg * 8;
        float4 a = *(const float4*)p;
        float4 b = *(const float4*)(p + 4);
        bf16x8 fr;
        fr[0]=(short)f2bf(a.x); fr[1]=(short)f2bf(a.y); fr[2]=(short)f2bf(a.z); fr[3]=(short)f2bf(a.w);
        fr[4]=(short)f2bf(b.x); fr[5]=(short)f2bf(b.y); fr[6]=(short)f2bf(b.z); fr[7]=(short)f2bf(b.w);
        Bw[jj][kk] = fr;
      }
    }
    for (int mi = 0; mi < 7; ++mi) {
      bf16x8 A[4];
#pragma unroll
      for (int kk = 0; kk < 4; ++kk)
        A[kk] = *(const bf16x8*)&xs_o[swz(mi * 16 + lm, kk * 32 + lg * 8)];
#pragma unroll
      for (int jj = 0; jj < 3; ++jj) {
        int njg = jj * 8 + wv;
        f32x4 acc = {0.f, 0.f, 0.f, 0.f};
#pragma unroll
        for (int kk = 0; kk < 4; ++kk)
          acc = __builtin_amdgcn_mfma_f32_16x16x32_bf16(A[kk], Bw[jj][kk], acc, 0, 0, 0);
#pragma unroll
        for (int r = 0; r < 4; ++r) {
          int mrow = mi * 16 + lg * 4 + r;    // C/D: row=(lane>>4)*4+reg, col=lane&15
          unsigned short uv = f2bf(acc[r] + bval[jj]);
          if (njg < 8)        p2[0][swz(mrow, njg * 16 + lm)] = uv;          // q
          else if (njg < 16)  kb[swz(mrow, (njg - 8) * 16 + lm)] = uv;       // k
          else                vT[swz((njg - 16) * 16 + lm, mrow)] = uv;      // v^T
        }
      }
    }
  }
  __syncthreads();

  // ---- extract per-wave Q A-fragments (unit u = (head-in-group, m-tile)) ----
  bf16x8 aq[2][2];
  const int u0 = wv, u1 = wv + 8;             // 14 units per head-group over 8 waves
#pragma unroll
  for (int g = 0; g < 2; ++g) {
    if (u0 < 14) aq[g][0] = *(const bf16x8*)&p2[0][swz((u0 % 7) * 16 + lm, (2*g + u0/7) * 32 + lg * 8)];
    if (u1 < 14) aq[g][1] = *(const bf16x8*)&p2[0][swz((u1 % 7) * 16 + lm, (2*g + u1/7) * 32 + lg * 8)];
  }
  __syncthreads();
  for (int v = tid; v < NPAD * 16; v += 512)  // q dead -> zero p2[0] K-pad cols
    p2[0][swz(v >> 4, 112 + (v & 15))] = 0;

  // ---------------- attention: 2 heads per pass, P double-buffered ----------------
#pragma unroll
  for (int g = 0; g < 2; ++g) {
#pragma unroll
    for (int j = 0; j < 2; ++j) {
      int u = (j == 0) ? u0 : u1;
      if (u < 14) {
        const int mi = u % 7, hh = u / 7, h = 2 * g + hh;
        f32x4 s[7];
#pragma unroll
        for (int nj = 0; nj < 7; ++nj) {      // QK^T: one K=32 MFMA per 16x16 tile
          bf16x8 bk = *(const bf16x8*)&kb[swz(nj * 16 + lm, h * 32 + lg * 8)];
          f32x4 z = {0.f, 0.f, 0.f, 0.f};
          s[nj] = __builtin_amdgcn_mfma_f32_16x16x32_bf16(aq[g][j], bk, z, 0, 0, 0);
        }
        int mc_n[7]; bool nval[7];
#pragma unroll
        for (int nj = 0; nj < 7; ++nj) {
          int n = nj * 16 + lm;
          nval[nj] = (n < NTOK);
          mc_n[nj] = mcode[nval[nj] ? n : 0];
        }
        const int mbase = mi * 16 + lg * 4;
#pragma unroll
        for (int r = 0; r < 4; ++r) {
          int m = mbase + r;
          int mc = m < NTOK ? m : NTOK - 1;   // clamp pad rows -> finite
          int mcm = mcode[mc];
          const float* mrowp = maskw + mc * NTOK;
          float mx = -1e30f;
#pragma unroll
          for (int nj = 0; nj < 7; ++nj) {
            float val;
            if (nval[nj]) {
              int n = nj * 16 + lm;
              val = s[nj][r] * SCALE + mrowp[n] + rpb[(mcm - mc_n[nj] + 253) * 4 + h];
            } else val = -1e30f;              // pad cols -> exp = 0
            s[nj][r] = val;
            mx = fmaxf(mx, val);
          }
          mx = fmaxf(mx, __shfl_xor(mx, 1));  // row lives in a 16-lane group
          mx = fmaxf(mx, __shfl_xor(mx, 2));
          mx = fmaxf(mx, __shfl_xor(mx, 4));
          mx = fmaxf(mx, __shfl_xor(mx, 8));
          float sum = 0.f;
#pragma unroll
          for (int nj = 0; nj < 7; ++nj) {
            float e = __expf(s[nj][r] - mx);
            s[nj][r] = e;
            sum += e;
          }
          sum += __shfl_xor(sum, 1);
          sum += __shfl_xor(sum, 2);
          sum += __shfl_xor(sum, 4);
          sum += __shfl_xor(sum, 8);
          float inv = 1.f / sum;
#pragma unroll
          for (int nj = 0; nj < 7; ++nj)
            p2[hh][swz(m, nj * 16 + lm)] = f2bf(s[nj][r] * inv);
        }
      }
    }
    __syncthreads();
    // PV: 28 tiles (2 heads x 7 m-tiles x 2 n-tiles) over 8 waves
#pragma unroll
    for (int tt = 0; tt < 4; ++tt) {
      int t = wv + tt * 8;
      if (t < 28) {
        int hh = t / 14, rem = t % 14, mi = rem >> 1, nt = rem & 1;
        int h = 2 * g + hh;
        f32x4 acc = {0.f, 0.f, 0.f, 0.f};
#pragma unroll
        for (int kk = 0; kk < 4; ++kk) {
          bf16x8 ap = *(const bf16x8*)&p2[hh][swz(mi * 16 + lm, kk * 32 + lg * 8)];
          bf16x8 bv = *(const bf16x8*)&vT[swz(h * 32 + nt * 16 + lm, kk * 32 + lg * 8)];
          acc = __builtin_amdgcn_mfma_f32_16x16x32_bf16(ap, bv, acc, 0, 0, 0);
        }
#pragma unroll
        for (int r = 0; r < 4; ++r)
          xs_o[swz(mi * 16 + lg * 4 + r, h * 32 + nt * 16 + lm)] = f2bf(acc[r]);
      }
    }
    __syncthreads();
  }

  // ---------------- GEMM3: out = o @ Wproj^T + b ----------------
  {
    bf16x8 Bp[4];
    int row = wv * 16 + lm;                   // wave wv owns output cols [wv*16, wv*16+16)
#pragma unroll
    for (int kk = 0; kk < 4; ++kk) {
      const float* p = proj_w + row * CDIM + kk * 32 + lg * 8;
      float4 a = *(const float4*)p;
      float4 b = *(const float4*)(p + 4);
      bf16x8 fr;
      fr[0]=(short)f2bf(a.x); fr[1]=(short)f2bf(a.y); fr[2]=(short)f2bf(a.z); fr[3]=(short)f2bf(a.w);
      fr[4]=(short)f2bf(b.x); fr[5]=(short)f2bf(b.y); fr[6]=(short)f2bf(b.z); fr[7]=(short)f2bf(b.w);
      Bp[kk] = fr;
    }
    float pb = proj_b[wv * 16 + lm];
    float* outb = out + (size_t)blk * (NTOK * CDIM);
    for (int mi = 0; mi < 7; ++mi) {
      f32x4 acc = {0.f, 0.f, 0.f, 0.f};
#pragma unroll
      for (int kk = 0; kk < 4; ++kk) {
        bf16x8 A = *(const bf16x8*)&xs_o[swz(mi * 16 + lm, kk * 32 + lg * 8)];
        acc = __builtin_amdgcn_mfma_f32_16x16x32_bf16(A, Bp[kk], acc, 0, 0, 0);
      }
#pragma unroll
      for (int r = 0; r < 4; ++r) {
        int m = mi * 16 + lg * 4 + r;
        if (m < NTOK) outb[m * CDIM + wv * 16 + lm] = acc[r] + pb;
      }
    }
  }
}

extern "C" void kernel_launch(void* const* d_in, const int* in_sizes, int n_in,
                              void* d_out, int out_size, void* d_ws, size_t ws_size,
                              hipStream_t stream) {
  const float* x      = (const float*)d_in[0];
  const float* mask   = (const float*)d_in[1];
  const float* qkv_w  = (const float*)d_in[2];
  const float* qkv_b  = (const float*)d_in[3];
  const float* rpb    = (const float*)d_in[4];
  const float* proj_w = (const float*)d_in[5];
  const float* proj_b = (const float*)d_in[6];
  int B  = in_sizes[0] / (NTOK * CDIM);
  int nW = in_sizes[1] / (NTOK * NTOK);
  hipLaunchKernelGGL(win_attn_kernel, dim3(B), dim3(512), 0, stream,
                     x, mask, qkv_w, qkv_b, rpb, proj_w, proj_b, (float*)d_out, nW);
}